// Round 14
// baseline (3227.231 us; speedup 1.0000x reference)
//
#include <hip/hip_runtime.h>
#include <hip/hip_bf16.h>

typedef __bf16 bf16;
typedef __bf16 bf16x8 __attribute__((ext_vector_type(8)));
typedef float  f32x4  __attribute__((ext_vector_type(4)));
typedef int    i32x4  __attribute__((ext_vector_type(4)));

#define TT    128
#define BB    1024
#define VOCAB 128
#define EE    256
#define HH    1024
#define NTAGS 8
#define PW    1034   // sW pitch (bf16) = 517 dw (odd) -> b128 reads 2-way max (free)

// dynamic LDS layout (identical to round-11 known-good: launches at 1 block/CU)
#define OFF_SW 0                                  // W_hh slice 64 x PW bf16 = 132352
#define OFF_ST (OFF_SW + 64 * PW * 2)             // h tile 64x72 bf16 = 9216
#define OFF_WO (OFF_ST + 64 * 72 * 2)             // W_out 8x64 f32 = 2048
#define OFF_ID (OFF_WO + NTAGS * 64 * 4)          // ids 64 int
#define OFF_SL (OFF_ID + 256)                     // seqlen 64 int
#define LDS_TOTAL (OFF_SL + 256)                  // 144128 B

#define BARSTRIDE 128                             // ints: 512 B per group counter

// ---------------------------------------------------------------- fp32 -> bf16
__global__ __launch_bounds__(256) void cvt_k(const float* __restrict__ s,
                                             bf16* __restrict__ d, int n) {
    int i = (blockIdx.x * 256 + threadIdx.x) * 4;
    if (i >= n) return;
    float4 v = *(const float4*)(s + i);
    bf16 o[4] = {(bf16)v.x, (bf16)v.y, (bf16)v.z, (bf16)v.w};
    *(short4*)(d + i) = *(short4*)o;
}

// ------------------------------------------- seq lengths + ids transpose
__global__ __launch_bounds__(256) void seqlen_k(const int* __restrict__ ids,
                                                int* __restrict__ sl,
                                                int* __restrict__ idsT) {
    int b = blockIdx.x * 256 + threadIdx.x;
    int c = 0;
    for (int t = 0; t < TT; ++t) {
        int v = ids[b * TT + t];
        idsT[t * BB + b] = v;
        c += (v != 0) ? 1 : 0;
    }
    sl[b] = c;
}

// ---------------------------------------------------------------- XP precompute
// XP[v][n] = emb[v,:] . W_ih[n,:] + b_ih[n] + b_hh[n]   (fp32, 128x1024)
__global__ __launch_bounds__(256) void xp_k(const float* __restrict__ emb,
                                            const float* __restrict__ W_ih,
                                            const float* __restrict__ b_ih,
                                            const float* __restrict__ b_hh,
                                            float* __restrict__ XP) {
    __shared__ float se[EE];
    const int v = blockIdx.x;
    se[threadIdx.x] = emb[v * EE + threadIdx.x];
    __syncthreads();
    const int c0 = threadIdx.x * 4;
    float s0 = 0.f, s1 = 0.f, s2 = 0.f, s3 = 0.f;
    for (int e = 0; e < EE; e += 4) {
        float4 ev = *(const float4*)(se + e);
        float4 w0 = *(const float4*)(W_ih + (c0 + 0) * EE + e);
        float4 w1 = *(const float4*)(W_ih + (c0 + 1) * EE + e);
        float4 w2 = *(const float4*)(W_ih + (c0 + 2) * EE + e);
        float4 w3 = *(const float4*)(W_ih + (c0 + 3) * EE + e);
        s0 += ev.x * w0.x + ev.y * w0.y + ev.z * w0.z + ev.w * w0.w;
        s1 += ev.x * w1.x + ev.y * w1.y + ev.z * w1.z + ev.w * w1.w;
        s2 += ev.x * w2.x + ev.y * w2.y + ev.z * w2.z + ev.w * w2.w;
        s3 += ev.x * w3.x + ev.y * w3.y + ev.z * w3.z + ev.w * w3.w;
    }
    XP[v * HH + c0 + 0] = s0 + b_ih[c0 + 0] + b_hh[c0 + 0];
    XP[v * HH + c0 + 1] = s1 + b_ih[c0 + 1] + b_hh[c0 + 1];
    XP[v * HH + c0 + 2] = s2 + b_ih[c0 + 2] + b_hh[c0 + 2];
    XP[v * HH + c0 + 3] = s3 + b_ih[c0 + 3] + b_hh[c0 + 3];
}

// ---------------------------------------------------------------- persistent RNN
// Round-11 structure, ONE semantic change: h exchange goes through VOLATILE
// accesses (sc0 sc1 -> bypass L1+L2, meet the write-through stores at the
// device coherence point) and the per-step agent acquire fence is REMOVED.
// Read-only data (XP, idsT, LDS-resident W) keeps its L2 warmth across all
// 128 steps because nothing invalidates the caches anymore.
__global__ __launch_bounds__(256, 1)
void rnn_persist(const int*   __restrict__ idsT,
                 const float* __restrict__ XP,
                 const bf16*  __restrict__ Whh,
                 const float* __restrict__ W_out,
                 const int*   __restrict__ sl,
                 bf16* h0, bf16* h1,
                 float* __restrict__ y_part,   // [16][TT][BB][NTAGS] step-major
                 unsigned* __restrict__ bar)
{
    extern __shared__ __align__(16) char smem[];
    bf16*  sW   = (bf16*)(smem + OFF_SW);
    bf16*  sT   = (bf16*)(smem + OFF_ST);
    float* sWo  = (float*)(smem + OFF_WO);
    int*   sIds = (int*)(smem + OFF_ID);
    int*   sSl  = (int*)(smem + OFF_SL);

    const int tid = threadIdx.x;
    // XCD-local group mapping (perf heuristic; correctness is coherence-point)
    const int xcd = blockIdx.x & 7;
    const int w   = blockIdx.x >> 3;
    const int gm  = xcd * 2 + (w >> 4);
    const int gn  = w & 15;
    const int Mbase = gm * 64, Nbase = gn * 64;

    // one-time staging
    for (int i = tid; i < 64 * 128; i += 256) {
        int n = i >> 7, g = i & 127;
        *(int4*)(sW + n * PW + g * 8) =
            *(const int4*)(Whh + (size_t)(Nbase + n) * HH + g * 8);
    }
    if (tid < 128) {
        int tg = tid >> 4, c = (tid & 15) * 4;
        *(float4*)(sWo + tg * 64 + c) = *(const float4*)(W_out + tg * HH + Nbase + c);
    }
    if (tid < 64) sSl[tid] = sl[Mbase + tid];
    __syncthreads();

    const int wave = tid >> 6, lane = tid & 63;
    const int quad = lane >> 4, l15 = lane & 15;
    const int wm = (wave >> 1) * 32, wn = (wave & 1) * 32;
    const bf16* pB0 = sW + (wn + l15) * PW;
    const bf16* pB1 = sW + (wn + 16 + l15) * PW;

    unsigned tgt = 0;
    for (int s = 0; s < TT; ++s) {
        const bf16* hp = (s & 1) ? h1 : h0;
        bf16*       hn = (s & 1) ? h0 : h1;

        if (tid < 64) sIds[tid] = idsT[s * BB + Mbase + tid];  // coalesced 256 B
        __syncthreads();   // sIds visible to all waves before epilogue reads

        f32x4 acc[2][2];
#pragma unroll
        for (int a = 0; a < 2; ++a)
#pragma unroll
            for (int b = 0; b < 2; ++b) {
                f32x4 z = {0.f, 0.f, 0.f, 0.f};
                acc[a][b] = z;
            }

        // ---- K-loop: A via VOLATILE loads (bypass L1/L2 -> coherence point),
        // 4-deep rotation; B from LDS; no barriers.
        const bf16* pa0 = hp + (size_t)(Mbase + wm + l15) * HH + quad * 8;
        const bf16* pa1 = pa0 + (size_t)16 * HH;
        i32x4 ca0[4], ca1[4];
#pragma unroll
        for (int u = 0; u < 4; ++u) {
            ca0[u] = *(volatile const i32x4*)(pa0 + u * 32);
            ca1[u] = *(volatile const i32x4*)(pa1 + u * 32);
        }
#pragma unroll
        for (int jj = 0; jj < 32; jj += 4) {
            i32x4 na0[4], na1[4];
            if (jj < 28) {
#pragma unroll
                for (int u = 0; u < 4; ++u) {
                    na0[u] = *(volatile const i32x4*)(pa0 + (jj + 4 + u) * 32);
                    na1[u] = *(volatile const i32x4*)(pa1 + (jj + 4 + u) * 32);
                }
            }
#pragma unroll
            for (int u = 0; u < 4; ++u) {
                const int j = jj + u;
                bf16x8 b0 = *(const bf16x8*)(pB0 + j * 32 + quad * 8);
                bf16x8 b1 = *(const bf16x8*)(pB1 + j * 32 + quad * 8);
                bf16x8 a0 = __builtin_bit_cast(bf16x8, ca0[u]);
                bf16x8 a1 = __builtin_bit_cast(bf16x8, ca1[u]);
                acc[0][0] = __builtin_amdgcn_mfma_f32_16x16x32_bf16(a0, b0, acc[0][0], 0, 0, 0);
                acc[0][1] = __builtin_amdgcn_mfma_f32_16x16x32_bf16(a0, b1, acc[0][1], 0, 0, 0);
                acc[1][0] = __builtin_amdgcn_mfma_f32_16x16x32_bf16(a1, b0, acc[1][0], 0, 0, 0);
                acc[1][1] = __builtin_amdgcn_mfma_f32_16x16x32_bf16(a1, b1, acc[1][1], 0, 0, 0);
            }
            if (jj < 28) {
#pragma unroll
                for (int u = 0; u < 4; ++u) { ca0[u] = na0[u]; ca1[u] = na1[u]; }
            }
        }

        // ---- epilogue: XP gather first (L2-warm, never invalidated), then
        // tanh + mask -> sT; mask fallback via volatile u16 (coherence point)
        float xv[2][2][4];
#pragma unroll
        for (int sm = 0; sm < 2; ++sm)
#pragma unroll
            for (int sn = 0; sn < 2; ++sn)
#pragma unroll
                for (int rr = 0; rr < 4; ++rr) {
                    int row = wm + sm * 16 + quad * 4 + rr;
                    int col = wn + sn * 16 + l15;
                    xv[sm][sn][rr] = XP[(size_t)sIds[row] * HH + Nbase + col];
                }
#pragma unroll
        for (int sm = 0; sm < 2; ++sm)
#pragma unroll
            for (int sn = 0; sn < 2; ++sn)
#pragma unroll
                for (int rr = 0; rr < 4; ++rr) {
                    int row = wm + sm * 16 + quad * 4 + rr;
                    int col = wn + sn * 16 + l15;
                    float pre = acc[sm][sn][rr] + xv[sm][sn][rr];
                    pre = fminf(15.f, fmaxf(-15.f, pre));
                    float e = __expf(2.f * pre);
                    float nh = (e - 1.f) / (e + 1.f);
                    bf16 hv;
                    if (s < sSl[row]) hv = (bf16)nh;
                    else {
                        unsigned short us = *(volatile const unsigned short*)
                            (hp + (size_t)(Mbase + row) * HH + Nbase + col);
                        hv = __builtin_bit_cast(bf16, us);
                    }
                    sT[row * 72 + col] = hv;
                }
        __syncthreads();

        // ---- h store (VOLATILE write-through to coherence point) + logits
        {
            const int r = tid >> 2, q = tid & 3;
            const bf16* srcp = sT + r * 72 + q * 16;
            i32x4 w0 = *(const i32x4*)(srcp);
            i32x4 w1 = *(const i32x4*)(srcp + 8);
            bf16* hd = hn + (size_t)(Mbase + r) * HH + Nbase + q * 16;
            *(volatile i32x4*)(hd)     = w0;
            *(volatile i32x4*)(hd + 8) = w1;

            bf16x8 hv0 = __builtin_bit_cast(bf16x8, w0);
            bf16x8 hv1 = __builtin_bit_cast(bf16x8, w1);
            float lg[NTAGS];
#pragma unroll
            for (int tg = 0; tg < NTAGS; ++tg) {
                const float* ww = sWo + tg * 64 + q * 16;
                float p = 0.f;
#pragma unroll
                for (int j = 0; j < 8; ++j) p += (float)hv0[j] * ww[j];
#pragma unroll
                for (int j = 0; j < 8; ++j) p += (float)hv1[j] * ww[8 + j];
                p += __shfl_xor(p, 1);
                p += __shfl_xor(p, 2);
                lg[tg] = p;
            }
            // step-major dense: block writes 64 rows x 32 B contiguous (2 KB)
            float* yb = y_part + (((size_t)gn * TT + s) * BB + Mbase + r) * NTAGS
                      + 2 * q;
            yb[0] = lg[2 * q];
            yb[1] = lg[2 * q + 1];
        }

        // ---- group barrier: relaxed arrival/poll. NO acquire fence — all h
        // traffic is volatile (coherence-point), stores drained pre-arrival
        // by the syncthreads vmcnt drain.
        __syncthreads();
        tgt += 16;
        if (tid == 0) {
            __hip_atomic_fetch_add(&bar[gm * BARSTRIDE], 1u, __ATOMIC_RELAXED,
                                   __HIP_MEMORY_SCOPE_AGENT);
            while (__hip_atomic_load(&bar[gm * BARSTRIDE], __ATOMIC_RELAXED,
                                     __HIP_MEMORY_SCOPE_AGENT) < tgt)
                __builtin_amdgcn_s_sleep(1);
        }
        __syncthreads();
    }
}

// ---------------------------------------------------------------- reduce + bias
__global__ __launch_bounds__(256) void reduce_bias_k(const float* __restrict__ yp,
                                                     const float* __restrict__ b_out,
                                                     float* __restrict__ out) {
    int idx = blockIdx.x * 256 + threadIdx.x;     // 512 blocks -> 131072 (t,b)
    int t = idx >> 10, b = idx & 1023;
    float4 s0 = *(const float4*)(b_out);
    float4 s1 = *(const float4*)(b_out + 4);
#pragma unroll
    for (int gn = 0; gn < 16; ++gn) {
        const float* p = yp + (((size_t)gn * TT + t) * BB + b) * NTAGS;
        float4 a = *(const float4*)(p);
        float4 c = *(const float4*)(p + 4);
        s0.x += a.x; s0.y += a.y; s0.z += a.z; s0.w += a.w;
        s1.x += c.x; s1.y += c.y; s1.z += c.z; s1.w += c.w;
    }
    float* o = out + ((size_t)b * TT + t) * NTAGS;
    *(float4*)(o)     = s0;
    *(float4*)(o + 4) = s1;
}

// ---------------------------------------------------------------- launch
extern "C" void kernel_launch(void* const* d_in, const int* in_sizes, int n_in,
                              void* d_out, int out_size, void* d_ws, size_t ws_size,
                              hipStream_t stream) {
    const int*   ids   = (const int*)d_in[0];
    const float* emb   = (const float*)d_in[1];
    const float* W_ih  = (const float*)d_in[2];
    const float* W_hh  = (const float*)d_in[3];
    const float* b_ih  = (const float*)d_in[4];
    const float* b_hh  = (const float*)d_in[5];
    const float* W_out = (const float*)d_in[6];
    const float* b_out = (const float*)d_in[7];
    float* out = (float*)d_out;

    // ws: sl | idsT | XP | Whh16 | h0 | h1 | y_part[16] | bar  (~71.2 MB)
    char* ws = (char*)d_ws;
    size_t off = 0;
    int*      sl     = (int*)(ws + off);      off += 4096;
    int*      idsT   = (int*)(ws + off);      off += (size_t)BB * TT * 4;
    float*    XP     = (float*)(ws + off);    off += (size_t)VOCAB * HH * 4;
    bf16*     Whh16  = (bf16*)(ws + off);     off += (size_t)HH * HH * 2;
    bf16*     h0     = (bf16*)(ws + off);     off += (size_t)BB * HH * 2;
    bf16*     h1     = (bf16*)(ws + off);     off += (size_t)BB * HH * 2;
    float*    y_part = (float*)(ws + off);    off += (size_t)16 * BB * TT * NTAGS * 4;
    unsigned* bar    = (unsigned*)(ws + off); off += 16 * BARSTRIDE * 4;
    if (ws_size < off) return;   // leaves out==0 -> clean diagnostic (err = max|ref|)

    (void)hipMemsetAsync(bar, 0, 16 * BARSTRIDE * 4, stream);
    (void)hipMemsetAsync(h0, 0, (size_t)BB * HH * 2, stream);

    cvt_k<<<(HH * HH / 4 + 255) / 256, 256, 0, stream>>>(W_hh, Whh16, HH * HH);
    xp_k<<<VOCAB, 256, 0, stream>>>(emb, W_ih, b_ih, b_hh, XP);
    seqlen_k<<<4, 256, 0, stream>>>(ids, sl, idsT);

    (void)hipFuncSetAttribute((const void*)rnn_persist,
                              hipFuncAttributeMaxDynamicSharedMemorySize, LDS_TOTAL);
    {
        const int*   a0 = idsT; const float* a1 = XP;  const bf16* a2 = Whh16;
        const float* a3 = W_out; const int*  a4 = sl;
        bf16* a5 = h0; bf16* a6 = h1; float* a7 = y_part; unsigned* a8 = bar;
        void* args[] = {&a0, &a1, &a2, &a3, &a4, &a5, &a6, &a7, &a8};
        (void)hipLaunchCooperativeKernel((const void*)rnn_persist, dim3(256), dim3(256),
                                         args, LDS_TOTAL, stream);
    }

    reduce_bias_k<<<BB * TT / 256, 256, 0, stream>>>(y_part, b_out, out);
}

// Round 15
// 1609.801 us; speedup vs baseline: 2.0047x; 2.0047x over previous
//
#include <hip/hip_runtime.h>
#include <hip/hip_bf16.h>

typedef __bf16 bf16;
typedef __bf16 bf16x8 __attribute__((ext_vector_type(8)));
typedef float  f32x4  __attribute__((ext_vector_type(4)));

#define TT    128
#define BB    1024
#define VOCAB 128
#define EE    256
#define HH    1024
#define NTAGS 8
#define PW    1034   // sW pitch (bf16) = 517 dw (odd) -> b128 reads 2-way max (free)

// dynamic LDS layout (round-11 proven: launches at 1 block/CU, 256 blocks)
#define OFF_SW 0                                  // W_hh slice 64 x PW bf16 = 132352
#define OFF_ST (OFF_SW + 64 * PW * 2)             // h tile 64x72 bf16 = 9216
#define OFF_WO (OFF_ST + 64 * 72 * 2)             // W_out 8x64 f32 = 2048
#define OFF_ID (OFF_WO + NTAGS * 64 * 4)          // ids 64 int
#define OFF_SL (OFF_ID + 256)                     // seqlen 64 int
#define LDS_TOTAL (OFF_SL + 256)                  // 144128 B dynamic (+4 static)

#define BARSTRIDE 128                             // ints: 512 B per group counter

// ---------------------------------------------------------------- fp32 -> bf16
__global__ __launch_bounds__(256) void cvt_k(const float* __restrict__ s,
                                             bf16* __restrict__ d, int n) {
    int i = (blockIdx.x * 256 + threadIdx.x) * 4;
    if (i >= n) return;
    float4 v = *(const float4*)(s + i);
    bf16 o[4] = {(bf16)v.x, (bf16)v.y, (bf16)v.z, (bf16)v.w};
    *(short4*)(d + i) = *(short4*)o;
}

// ------------------------------------------- seq lengths + ids transpose
__global__ __launch_bounds__(256) void seqlen_k(const int* __restrict__ ids,
                                                int* __restrict__ sl,
                                                int* __restrict__ idsT) {
    int b = blockIdx.x * 256 + threadIdx.x;
    int c = 0;
    for (int t = 0; t < TT; ++t) {
        int v = ids[b * TT + t];
        idsT[t * BB + b] = v;
        c += (v != 0) ? 1 : 0;
    }
    sl[b] = c;
}

// ---------------------------------------------------------------- XP precompute
// XP[v][n] = emb[v,:] . W_ih[n,:] + b_ih[n] + b_hh[n]   (fp32, 128x1024)
__global__ __launch_bounds__(256) void xp_k(const float* __restrict__ emb,
                                            const float* __restrict__ W_ih,
                                            const float* __restrict__ b_ih,
                                            const float* __restrict__ b_hh,
                                            float* __restrict__ XP) {
    __shared__ float se[EE];
    const int v = blockIdx.x;
    se[threadIdx.x] = emb[v * EE + threadIdx.x];
    __syncthreads();
    const int c0 = threadIdx.x * 4;
    float s0 = 0.f, s1 = 0.f, s2 = 0.f, s3 = 0.f;
    for (int e = 0; e < EE; e += 4) {
        float4 ev = *(const float4*)(se + e);
        float4 w0 = *(const float4*)(W_ih + (c0 + 0) * EE + e);
        float4 w1 = *(const float4*)(W_ih + (c0 + 1) * EE + e);
        float4 w2 = *(const float4*)(W_ih + (c0 + 2) * EE + e);
        float4 w3 = *(const float4*)(W_ih + (c0 + 3) * EE + e);
        s0 += ev.x * w0.x + ev.y * w0.y + ev.z * w0.z + ev.w * w0.w;
        s1 += ev.x * w1.x + ev.y * w1.y + ev.z * w1.z + ev.w * w1.w;
        s2 += ev.x * w2.x + ev.y * w2.y + ev.z * w2.z + ev.w * w2.w;
        s3 += ev.x * w3.x + ev.y * w3.y + ev.z * w3.z + ev.w * w3.w;
    }
    XP[v * HH + c0 + 0] = s0 + b_ih[c0 + 0] + b_hh[c0 + 0];
    XP[v * HH + c0 + 1] = s1 + b_ih[c0 + 1] + b_hh[c0 + 1];
    XP[v * HH + c0 + 2] = s2 + b_ih[c0 + 2] + b_hh[c0 + 2];
    XP[v * HH + c0 + 3] = s3 + b_ih[c0 + 3] + b_hh[c0 + 3];
}

// ---------------------------------------------------------------- persistent RNN
// Round-11 structure; ONE semantic unit changed: XCD-LOCAL h exchange.
// Groups formed at runtime from the physical XCC_ID (pigeonhole: coop launch
// + 144KB LDS -> 1 block/CU -> exactly 32 blocks/XCD), so each gm-group's h
// slab is produced & consumed within one XCD's shared L2. h stores are PLAIN
// (L1 is write-through -> lands in XCD L2); consumers invalidate only L1
// (`buffer_inv sc0`) after the barrier — L2 stays warm (XP/idsT/A refills).
__global__ __launch_bounds__(256, 1)
void rnn_persist(const int*   __restrict__ idsT,
                 const float* __restrict__ XP,
                 const bf16*  __restrict__ Whh,
                 const float* __restrict__ W_out,
                 const int*   __restrict__ sl,
                 bf16* h0, bf16* h1,
                 float* __restrict__ y_part,   // [16][TT][BB][NTAGS] step-major
                 unsigned* __restrict__ bar,
                 unsigned* __restrict__ xcnt)  // [8] per-XCD rank counters
{
    extern __shared__ __align__(16) char smem[];
    bf16*  sW   = (bf16*)(smem + OFF_SW);
    bf16*  sT   = (bf16*)(smem + OFF_ST);
    float* sWo  = (float*)(smem + OFF_WO);
    int*   sIds = (int*)(smem + OFF_ID);
    int*   sSl  = (int*)(smem + OFF_SL);
    __shared__ int sGrp;

    const int tid = threadIdx.x;

    // ---- runtime XCD-exact group assignment (correct by construction)
    if (tid == 0) {
        unsigned xcc;
        asm volatile("s_getreg_b32 %0, hwreg(HW_REG_XCC_ID)" : "=s"(xcc));
        xcc &= 7;
        unsigned r = __hip_atomic_fetch_add(&xcnt[xcc], 1u, __ATOMIC_RELAXED,
                                            __HIP_MEMORY_SCOPE_AGENT);
        sGrp = (int)(xcc * 32 + (r & 31));
    }
    __syncthreads();
    const int g  = sGrp;
    const int gm = g >> 4;          // 2 gm-groups per XCD, 16 blocks each
    const int gn = g & 15;
    const int Mbase = gm * 64, Nbase = gn * 64;

    // one-time staging
    for (int i = tid; i < 64 * 128; i += 256) {
        int n = i >> 7, gg = i & 127;
        *(int4*)(sW + n * PW + gg * 8) =
            *(const int4*)(Whh + (size_t)(Nbase + n) * HH + gg * 8);
    }
    if (tid < 128) {
        int tg = tid >> 4, c = (tid & 15) * 4;
        *(float4*)(sWo + tg * 64 + c) = *(const float4*)(W_out + tg * HH + Nbase + c);
    }
    if (tid < 64) sSl[tid] = sl[Mbase + tid];
    __syncthreads();

    const int wave = tid >> 6, lane = tid & 63;
    const int quad = lane >> 4, l15 = lane & 15;
    const int wm = (wave >> 1) * 32, wn = (wave & 1) * 32;
    const bf16* pB0 = sW + (wn + l15) * PW;
    const bf16* pB1 = sW + (wn + 16 + l15) * PW;

    unsigned tgt = 0;
    for (int s = 0; s < TT; ++s) {
        const bf16* hp = (s & 1) ? h1 : h0;
        bf16*       hn = (s & 1) ? h0 : h1;

        if (tid < 64) sIds[tid] = idsT[s * BB + Mbase + tid];  // coalesced 256 B
        __syncthreads();   // sIds visible to all waves before epilogue reads

        f32x4 acc[2][2];
#pragma unroll
        for (int a = 0; a < 2; ++a)
#pragma unroll
            for (int b = 0; b < 2; ++b) {
                f32x4 z = {0.f, 0.f, 0.f, 0.f};
                acc[a][b] = z;
            }

        // ---- K-loop: A plain loads (XCD-L2 hits), 4-deep rotation; B LDS
        const bf16* pa0 = hp + (size_t)(Mbase + wm + l15) * HH + quad * 8;
        const bf16* pa1 = pa0 + (size_t)16 * HH;
        int4 ca0[4], ca1[4];
#pragma unroll
        for (int u = 0; u < 4; ++u) {
            ca0[u] = *(const int4*)(pa0 + u * 32);
            ca1[u] = *(const int4*)(pa1 + u * 32);
        }
#pragma unroll
        for (int jj = 0; jj < 32; jj += 4) {
            int4 na0[4], na1[4];
            if (jj < 28) {
#pragma unroll
                for (int u = 0; u < 4; ++u) {
                    na0[u] = *(const int4*)(pa0 + (jj + 4 + u) * 32);
                    na1[u] = *(const int4*)(pa1 + (jj + 4 + u) * 32);
                }
            }
#pragma unroll
            for (int u = 0; u < 4; ++u) {
                const int j = jj + u;
                bf16x8 b0 = *(const bf16x8*)(pB0 + j * 32 + quad * 8);
                bf16x8 b1 = *(const bf16x8*)(pB1 + j * 32 + quad * 8);
                bf16x8 a0 = __builtin_bit_cast(bf16x8, ca0[u]);
                bf16x8 a1 = __builtin_bit_cast(bf16x8, ca1[u]);
                acc[0][0] = __builtin_amdgcn_mfma_f32_16x16x32_bf16(a0, b0, acc[0][0], 0, 0, 0);
                acc[0][1] = __builtin_amdgcn_mfma_f32_16x16x32_bf16(a0, b1, acc[0][1], 0, 0, 0);
                acc[1][0] = __builtin_amdgcn_mfma_f32_16x16x32_bf16(a1, b0, acc[1][0], 0, 0, 0);
                acc[1][1] = __builtin_amdgcn_mfma_f32_16x16x32_bf16(a1, b1, acc[1][1], 0, 0, 0);
            }
            if (jj < 28) {
#pragma unroll
                for (int u = 0; u < 4; ++u) { ca0[u] = na0[u]; ca1[u] = na1[u]; }
            }
        }

        // ---- epilogue: XP gather first (L2-warm), then tanh + mask -> sT
        float xv[2][2][4];
#pragma unroll
        for (int sm = 0; sm < 2; ++sm)
#pragma unroll
            for (int sn = 0; sn < 2; ++sn)
#pragma unroll
                for (int rr = 0; rr < 4; ++rr) {
                    int row = wm + sm * 16 + quad * 4 + rr;
                    int col = wn + sn * 16 + l15;
                    xv[sm][sn][rr] = XP[(size_t)sIds[row] * HH + Nbase + col];
                }
#pragma unroll
        for (int sm = 0; sm < 2; ++sm)
#pragma unroll
            for (int sn = 0; sn < 2; ++sn)
#pragma unroll
                for (int rr = 0; rr < 4; ++rr) {
                    int row = wm + sm * 16 + quad * 4 + rr;
                    int col = wn + sn * 16 + l15;
                    float pre = acc[sm][sn][rr] + xv[sm][sn][rr];
                    pre = fminf(15.f, fmaxf(-15.f, pre));
                    float e = __expf(2.f * pre);
                    float nh = (e - 1.f) / (e + 1.f);
                    bf16 hv;
                    if (s < sSl[row]) hv = (bf16)nh;
                    else hv = hp[(size_t)(Mbase + row) * HH + Nbase + col];
                    sT[row * 72 + col] = hv;
                }
        __syncthreads();

        // ---- h store: PLAIN stores (write-through L1 -> shared XCD L2) + logits
        {
            const int r = tid >> 2, q = tid & 3;
            const bf16* srcp = sT + r * 72 + q * 16;
            int4 w0 = *(const int4*)(srcp);
            int4 w1 = *(const int4*)(srcp + 8);
            bf16* hd = hn + (size_t)(Mbase + r) * HH + Nbase + q * 16;
            *(int4*)(hd)     = w0;
            *(int4*)(hd + 8) = w1;

            bf16x8 hv0 = __builtin_bit_cast(bf16x8, w0);
            bf16x8 hv1 = __builtin_bit_cast(bf16x8, w1);
            float lg[NTAGS];
#pragma unroll
            for (int tg = 0; tg < NTAGS; ++tg) {
                const float* ww = sWo + tg * 64 + q * 16;
                float p = 0.f;
#pragma unroll
                for (int j = 0; j < 8; ++j) p += (float)hv0[j] * ww[j];
#pragma unroll
                for (int j = 0; j < 8; ++j) p += (float)hv1[j] * ww[8 + j];
                p += __shfl_xor(p, 1);
                p += __shfl_xor(p, 2);
                lg[tg] = p;
            }
            // step-major dense: block writes 64 rows x 32 B contiguous (2 KB)
            float* yb = y_part + (((size_t)gn * TT + s) * BB + Mbase + r) * NTAGS
                      + 2 * q;
            yb[0] = lg[2 * q];
            yb[1] = lg[2 * q + 1];
        }

        // ---- group barrier: syncthreads drains vmcnt (h stores in XCD L2),
        // relaxed arrival/poll, then L1-ONLY invalidate (L2 stays warm).
        __syncthreads();
        tgt += 16;
        if (tid == 0) {
            __hip_atomic_fetch_add(&bar[gm * BARSTRIDE], 1u, __ATOMIC_RELAXED,
                                   __HIP_MEMORY_SCOPE_AGENT);
            unsigned spins = 0;
            while (__hip_atomic_load(&bar[gm * BARSTRIDE], __ATOMIC_RELAXED,
                                     __HIP_MEMORY_SCOPE_AGENT) < tgt) {
                __builtin_amdgcn_s_sleep(1);
                if (++spins > (1u << 24)) break;   // hang valve -> wrong-answer
            }
            asm volatile("buffer_inv sc0" ::: "memory");  // invalidate L1 only
        }
        __syncthreads();
    }
}

// ---------------------------------------------------------------- reduce + bias
__global__ __launch_bounds__(256) void reduce_bias_k(const float* __restrict__ yp,
                                                     const float* __restrict__ b_out,
                                                     float* __restrict__ out) {
    int idx = blockIdx.x * 256 + threadIdx.x;     // 512 blocks -> 131072 (t,b)
    int t = idx >> 10, b = idx & 1023;
    float4 s0 = *(const float4*)(b_out);
    float4 s1 = *(const float4*)(b_out + 4);
#pragma unroll
    for (int gn = 0; gn < 16; ++gn) {
        const float* p = yp + (((size_t)gn * TT + t) * BB + b) * NTAGS;
        float4 a = *(const float4*)(p);
        float4 c = *(const float4*)(p + 4);
        s0.x += a.x; s0.y += a.y; s0.z += a.z; s0.w += a.w;
        s1.x += c.x; s1.y += c.y; s1.z += c.z; s1.w += c.w;
    }
    float* o = out + ((size_t)b * TT + t) * NTAGS;
    *(float4*)(o)     = s0;
    *(float4*)(o + 4) = s1;
}

// ---------------------------------------------------------------- launch
extern "C" void kernel_launch(void* const* d_in, const int* in_sizes, int n_in,
                              void* d_out, int out_size, void* d_ws, size_t ws_size,
                              hipStream_t stream) {
    const int*   ids   = (const int*)d_in[0];
    const float* emb   = (const float*)d_in[1];
    const float* W_ih  = (const float*)d_in[2];
    const float* W_hh  = (const float*)d_in[3];
    const float* b_ih  = (const float*)d_in[4];
    const float* b_hh  = (const float*)d_in[5];
    const float* W_out = (const float*)d_in[6];
    const float* b_out = (const float*)d_in[7];
    float* out = (float*)d_out;

    // ws: sl | idsT | XP | Whh16 | h0 | h1 | y_part[16] | bar | xcnt (~71.2 MB)
    char* ws = (char*)d_ws;
    size_t off = 0;
    int*      sl     = (int*)(ws + off);      off += 4096;
    int*      idsT   = (int*)(ws + off);      off += (size_t)BB * TT * 4;
    float*    XP     = (float*)(ws + off);    off += (size_t)VOCAB * HH * 4;
    bf16*     Whh16  = (bf16*)(ws + off);     off += (size_t)HH * HH * 2;
    bf16*     h0     = (bf16*)(ws + off);     off += (size_t)BB * HH * 2;
    bf16*     h1     = (bf16*)(ws + off);     off += (size_t)BB * HH * 2;
    float*    y_part = (float*)(ws + off);    off += (size_t)16 * BB * TT * NTAGS * 4;
    unsigned* bar    = (unsigned*)(ws + off); off += 16 * BARSTRIDE * 4;
    unsigned* xcnt   = (unsigned*)(ws + off); off += 4096;
    if (ws_size < off) return;   // leaves out==0 -> clean diagnostic (err = max|ref|)

    (void)hipMemsetAsync(bar, 0, 16 * BARSTRIDE * 4, stream);
    (void)hipMemsetAsync(xcnt, 0, 4096, stream);
    (void)hipMemsetAsync(h0, 0, (size_t)BB * HH * 2, stream);

    cvt_k<<<(HH * HH / 4 + 255) / 256, 256, 0, stream>>>(W_hh, Whh16, HH * HH);
    xp_k<<<VOCAB, 256, 0, stream>>>(emb, W_ih, b_ih, b_hh, XP);
    seqlen_k<<<4, 256, 0, stream>>>(ids, sl, idsT);

    (void)hipFuncSetAttribute((const void*)rnn_persist,
                              hipFuncAttributeMaxDynamicSharedMemorySize, LDS_TOTAL);
    {
        const int*   a0 = idsT; const float* a1 = XP;  const bf16* a2 = Whh16;
        const float* a3 = W_out; const int*  a4 = sl;
        bf16* a5 = h0; bf16* a6 = h1; float* a7 = y_part;
        unsigned* a8 = bar; unsigned* a9 = xcnt;
        void* args[] = {&a0, &a1, &a2, &a3, &a4, &a5, &a6, &a7, &a8, &a9};
        (void)hipLaunchCooperativeKernel((const void*)rnn_persist, dim3(256), dim3(256),
                                         args, LDS_TOTAL, stream);
    }

    reduce_bias_k<<<BB * TT / 256, 256, 0, stream>>>(y_part, b_out, out);
}